// Round 4
// baseline (355.344 us; speedup 1.0000x reference)
//
#include <hip/hip_runtime.h>
#include <hip/hip_bf16.h>

// LightGCN layer: out = adj @ (x * (u >= 0.1) / 0.9)
// x: [16384,64] f32, adj: [16384,16384] f32, u: [16384,64] f32, out: [16384,64] f32
//
// Round 4: barrier-free wave-private streaming with a 2-deep register pipeline.
//  - 256 blocks x 4 waves; each wave owns 16 rows across FULL K. No __syncthreads
//    in the main loop: A staging LDS is wave-private, so ordering is pure
//    data-dependence (compiler emits counted vmcnt/lgkmcnt, never a full drain).
//  - Two A register sets: while STASH waits on A(t+1), A(t+2)'s 8 loads stay
//    outstanding -> DRAM never idles; waves de-phase and smooth demand.
//  - A loads: dwordx4, two 512B row-segments per instr (page-local).
//  - LDS layout write-contiguous (g*544 + half*272 + m*8): ds_write_b64 = 4
//    words/bank uniform, ds_read_b128 = 8 words/bank uniform (both minimal).
//  - B (2 MB bf16 frag-linear in d_ws) read directly from L2 in the MFMA loop.

#define NN 16384
#define DD 64
#define KP 128                 // K floats per phase
#define NPH (NN / KP)          // 128 phases
#define GSTRIDE 544            // 512B write-block + 32B pad
#define HSTRIDE 272
#define CHUNK (8 * GSTRIDE)    // 4352 B per staged phase (16 rows x 128 k bf16)

typedef __attribute__((ext_vector_type(4))) float floatx4;
typedef __attribute__((ext_vector_type(4))) short short4v;
typedef __attribute__((ext_vector_type(8))) short short8;

static __device__ __forceinline__ short bf16b(float f) {
    union { __hip_bfloat16 h; short s; } cv;
    cv.h = __float2bfloat16(f);
    return cv.s;
}

// B in MFMA fragment-linear order (unchanged, verified r1-r3):
// chunk c = s*256 + f*64 + lane; shorts at c*8:
// element j = B[s*32 + (lane>>4)*8 + j][f*16 + (lane&15)]
__global__ void __launch_bounds__(256) prep_kernel(const float* __restrict__ x,
                                                   const float* __restrict__ u,
                                                   short* __restrict__ bfrag) {
    int c = blockIdx.x * 256 + threadIdx.x;
    int lane = c & 63;
    int f = (c >> 6) & 3;
    int s = c >> 8;
    int col = f * 16 + (lane & 15);
    int k0 = s * 32 + (lane >> 4) * 8;
    short8 v;
#pragma unroll
    for (int j = 0; j < 8; ++j) {
        int idx = (k0 + j) * DD + col;
        float xv = x[idx];
        float uv = u[idx];
        float xd = (uv >= 0.1f) ? xv * (1.0f / 0.9f) : 0.0f;
        v[j] = bf16b(xd);
    }
    *reinterpret_cast<short8*>(bfrag + (size_t)c * 8) = v;
}

__global__ void __launch_bounds__(256, 1) gemm_kernel(const float* __restrict__ adj,
                                                      const short* __restrict__ bfrag,
                                                      float* __restrict__ out) {
    __shared__ char smem[4 * 2 * CHUNK];   // 34,816 B: per-wave private dbuf

    const int tid  = threadIdx.x;
    const int lane = tid & 63;
    const int w    = tid >> 6;
    const int r    = lane & 15;           // MFMA A-row
    const int kg   = lane >> 4;           // MFMA k-group
    const int row0 = blockIdx.x * 64 + w * 16;

    char* c0 = smem + w * 2 * CHUNK;
    char* c1 = c0 + CHUNK;

    // A-load addressing: instr g covers rows {2g, 2g+1}, 512B contiguous per row
    const int lrow = lane >> 5;            // 0/1: which of the 2 rows
    const int lm   = lane & 31;            // position within the 512B row-segment
    const float* abase = adj + (size_t)(row0 + lrow) * NN + lm * 4;
    // stash addressing (write-contiguous layout)
    const int sbyte = lrow * HSTRIDE + lm * 8;
    // A-frag read offset (derived inverse mapping; +s*64 + kg*16 per K-step)
    const int aoff = (r >> 1) * GSTRIDE + (r & 1) * HSTRIDE + kg * 16;

    floatx4 Sa[8], Sb[8];

#define ISSUE(TT, S)                                                              \
    {                                                                             \
        _Pragma("unroll")                                                         \
        for (int g = 0; g < 8; ++g)                                               \
            S[g] = *reinterpret_cast<const floatx4*>(                             \
                abase + (size_t)(2 * g) * NN + (size_t)(TT) * KP);                \
        asm volatile("" ::: "memory");                                            \
    }

#define STASH(S, C)                                                              \
    {                                                                            \
        _Pragma("unroll")                                                        \
        for (int g = 0; g < 8; ++g) {                                            \
            short4v bw;                                                          \
            bw.x = bf16b(S[g].x); bw.y = bf16b(S[g].y);                          \
            bw.z = bf16b(S[g].z); bw.w = bf16b(S[g].w);                          \
            *reinterpret_cast<short4v*>((C) + g * GSTRIDE + sbyte) = bw;         \
        }                                                                        \
    }

    floatx4 acc0 = {0.f, 0.f, 0.f, 0.f};
    floatx4 acc1 = {0.f, 0.f, 0.f, 0.f};
    floatx4 acc2 = {0.f, 0.f, 0.f, 0.f};
    floatx4 acc3 = {0.f, 0.f, 0.f, 0.f};

#define COMPUTE(TT, C)                                                           \
    {                                                                            \
        const char* bb = (const char*)bfrag + (size_t)(TT) * 16384 + lane * 16;  \
        for (int s = 0; s < 4; ++s) {                                            \
            short8 af = *reinterpret_cast<const short8*>((C) + aoff + s * 64);   \
            short8 b0 = *reinterpret_cast<const short8*>(bb + s * 4096);         \
            short8 b1 = *reinterpret_cast<const short8*>(bb + s * 4096 + 1024);  \
            short8 b2 = *reinterpret_cast<const short8*>(bb + s * 4096 + 2048);  \
            short8 b3 = *reinterpret_cast<const short8*>(bb + s * 4096 + 3072);  \
            acc0 = __builtin_amdgcn_mfma_f32_16x16x32_bf16(af, b0, acc0, 0, 0, 0);\
            acc1 = __builtin_amdgcn_mfma_f32_16x16x32_bf16(af, b1, acc1, 0, 0, 0);\
            acc2 = __builtin_amdgcn_mfma_f32_16x16x32_bf16(af, b2, acc2, 0, 0, 0);\
            acc3 = __builtin_amdgcn_mfma_f32_16x16x32_bf16(af, b3, acc3, 0, 0, 0);\
        }                                                                        \
    }

    // prolog: A0 -> Sa -> c0 (staged); A1 -> Sb (in flight)
    ISSUE(0, Sa);
    ISSUE(1, Sb);
    STASH(Sa, c0);   // waits Sa only (counted vmcnt: Sb stays outstanding)

    for (int t = 0; t < NPH; t += 2) {
        // invariant: c0 holds A(t); Sb holds A(t+1) in flight; Sa free
        if (t + 2 < NPH) ISSUE(t + 2, Sa);
        COMPUTE(t, c0);
        STASH(Sb, c1);                       // A(t+1); waits Sb, Sa outstanding
        if (t + 3 < NPH) ISSUE(t + 3, Sb);
        COMPUTE(t + 1, c1);
        if (t + 2 < NPH) STASH(Sa, c0);      // A(t+2); waits Sa, Sb outstanding
    }

    // C/D: col(N) = lane&15 = r, row(M) = kg*4 + j  (verified r1-r3)
    const int orow = row0 + kg * 4;
    float* op = out + (size_t)orow * DD + r;
#pragma unroll
    for (int j = 0; j < 4; ++j) {
        op[(size_t)j * DD + 0]  = acc0[j];
        op[(size_t)j * DD + 16] = acc1[j];
        op[(size_t)j * DD + 32] = acc2[j];
        op[(size_t)j * DD + 48] = acc3[j];
    }
}

extern "C" void kernel_launch(void* const* d_in, const int* in_sizes, int n_in,
                              void* d_out, int out_size, void* d_ws, size_t ws_size,
                              hipStream_t stream) {
    const float* x   = (const float*)d_in[0];
    const float* adj = (const float*)d_in[1];
    const float* u   = (const float*)d_in[2];
    float* out = (float*)d_out;
    short* bfrag = (short*)d_ws;   // 16384*64 bf16 = 2 MB

    prep_kernel<<<dim3(512), dim3(256), 0, stream>>>(x, u, bfrag);
    gemm_kernel<<<dim3(NN / 64), dim3(256), 0, stream>>>(adj, bfrag, out);
}

// Round 5
// 219.707 us; speedup vs baseline: 1.6174x; 1.6174x over previous
//
#include <hip/hip_runtime.h>
#include <hip/hip_bf16.h>

// LightGCN layer: out = adj @ (x * (u >= 0.1) / 0.9)
// x: [16384,64] f32, adj: [16384,16384] f32, u: [16384,64] f32, out: [16384,64] f32
//
// Round 5: barrier-free single-wave blocks, 2-deep register pipeline.
//  - vmcnt lesson from r4: vmcnt is IN-ORDER; any wait for a newer load drains
//    all older prefetches. So steady-state global loads = prefetch stream only,
//    consumed oldest-first. B (frag-linear bf16 in d_ws) is prefetched into
//    registers and used AS the MFMA fragments (r1/r2 mapping). Only A takes the
//    LDS transpose bounce (wave-private -> no barriers anywhere).
//  - 1024 blocks x 64 threads (1 wave, 16 rows, full K). 4 blocks/CU, fully
//    independent -> desynchronized demand keeps DRAM busy.
//  - Two reg sets (Aa/Ba, Ab/Bb): STASH(set X) waits X's loads while set Y's 12
//    loads stay outstanding -> compiler emits counted vmcnt, never 0.
//  - A LDS layout byte = s*1280 + r*80 + kg*16 + half*8:
//    ds_read_b128 (r=lane&15, kg=lane>>4): start bank (20r+4kg)%32 covers each
//    bank with exactly 8 words -> conflict-free. ds_write_b64 near-uniform.

#define NN 16384
#define DD 64
#define MT 16
#define KP 64                  // K floats per phase
#define NPH (NN / KP)          // 256 phases
#define CHUNK 2560             // 2 * 1280 B per staged A phase

typedef __attribute__((ext_vector_type(4))) float floatx4;
typedef __attribute__((ext_vector_type(4))) short short4v;
typedef __attribute__((ext_vector_type(8))) short short8;

static __device__ __forceinline__ short bf16b(float f) {
    union { __hip_bfloat16 h; short s; } cv;
    cv.h = __float2bfloat16(f);
    return cv.s;
}

// B in MFMA fragment-linear order (unchanged, verified r1-r4):
// chunk c = s*256 + f*64 + lane; shorts at c*8:
// element j = B[s*32 + (lane>>4)*8 + j][f*16 + (lane&15)]
__global__ void __launch_bounds__(256) prep_kernel(const float* __restrict__ x,
                                                   const float* __restrict__ u,
                                                   short* __restrict__ bfrag) {
    int c = blockIdx.x * 256 + threadIdx.x;
    int lane = c & 63;
    int f = (c >> 6) & 3;
    int s = c >> 8;
    int col = f * 16 + (lane & 15);
    int k0 = s * 32 + (lane >> 4) * 8;
    short8 v;
#pragma unroll
    for (int j = 0; j < 8; ++j) {
        int idx = (k0 + j) * DD + col;
        float xv = x[idx];
        float uv = u[idx];
        float xd = (uv >= 0.1f) ? xv * (1.0f / 0.9f) : 0.0f;
        v[j] = bf16b(xd);
    }
    *reinterpret_cast<short8*>(bfrag + (size_t)c * 8) = v;
}

__global__ void __launch_bounds__(64) gemm_kernel(const float* __restrict__ adj,
                                                  const short* __restrict__ bfrag,
                                                  float* __restrict__ out) {
    __shared__ char smem[2 * CHUNK];   // 5120 B, wave-private (1 wave/block)
    char* c0 = smem;
    char* c1 = smem + CHUNK;

    const int lane = threadIdx.x & 63;
    const int r    = lane & 15;        // MFMA A-row / output col
    const int kg   = lane >> 4;        // MFMA k-group
    const int row0 = blockIdx.x * MT;

    // A-load addressing: instr g covers rows {4g..4g+3}; 16 lanes x 16B = 256B/row
    const int lrow = lane >> 4;        // 0..3
    const int lm   = lane & 15;        // 16B slot within the 256B row-run
    // STASH addressing: lane holds (row = 4g+lrow, k = lm*4..+3)
    const int sbyte = (lm >> 3) * 1280 + lrow * 80 + (((lm & 7) >> 1) * 16) + (lm & 1) * 8;
    // A-frag read offset (+ s*1280 per K-step)
    const int aoff = r * 80 + kg * 16;

    const float* apA = adj + (size_t)(row0 + lrow) * NN + lm * 4;          // phase 0
    const float* apB = apA + KP;                                           // phase 1
    const short* bpA = bfrag + (size_t)lane * 8;                           // phase 0
    const short* bpB = bpA + 4096;                                         // phase 1

    floatx4 Aa[4], Ab[4];
    short8  Ba[8], Bb[8];

#define ISSUE_A(RA, AP)                                                        \
    {                                                                          \
        _Pragma("unroll")                                                      \
        for (int g = 0; g < 4; ++g)                                            \
            RA[g] = *reinterpret_cast<const floatx4*>(AP + (size_t)g * 4 * NN);\
        AP += 2 * KP;                                                          \
        asm volatile("" ::: "memory");                                         \
    }

#define ISSUE_B(RB, BP)                                                       \
    {                                                                         \
        _Pragma("unroll")                                                     \
        for (int s = 0; s < 2; ++s)                                           \
            _Pragma("unroll")                                                 \
            for (int f = 0; f < 4; ++f)                                       \
                RB[s * 4 + f] =                                               \
                    *reinterpret_cast<const short8*>(BP + s * 2048 + f * 512);\
        BP += 8192;                                                           \
        asm volatile("" ::: "memory");                                        \
    }

#define STASH(RA, C)                                                         \
    {                                                                        \
        _Pragma("unroll")                                                    \
        for (int g = 0; g < 4; ++g) {                                        \
            short4v w_;                                                      \
            w_.x = bf16b(RA[g].x); w_.y = bf16b(RA[g].y);                    \
            w_.z = bf16b(RA[g].z); w_.w = bf16b(RA[g].w);                    \
            *reinterpret_cast<short4v*>((C) + sbyte + g * 320) = w_;         \
        }                                                                    \
    }

    floatx4 acc0 = {0.f, 0.f, 0.f, 0.f};
    floatx4 acc1 = {0.f, 0.f, 0.f, 0.f};
    floatx4 acc2 = {0.f, 0.f, 0.f, 0.f};
    floatx4 acc3 = {0.f, 0.f, 0.f, 0.f};

#define COMPUTE(C, RB)                                                            \
    {                                                                             \
        _Pragma("unroll")                                                         \
        for (int s = 0; s < 2; ++s) {                                             \
            short8 af = *reinterpret_cast<const short8*>((C) + aoff + s * 1280);  \
            acc0 = __builtin_amdgcn_mfma_f32_16x16x32_bf16(af, RB[s*4+0], acc0, 0, 0, 0); \
            acc1 = __builtin_amdgcn_mfma_f32_16x16x32_bf16(af, RB[s*4+1], acc1, 0, 0, 0); \
            acc2 = __builtin_amdgcn_mfma_f32_16x16x32_bf16(af, RB[s*4+2], acc2, 0, 0, 0); \
            acc3 = __builtin_amdgcn_mfma_f32_16x16x32_bf16(af, RB[s*4+3], acc3, 0, 0, 0); \
        }                                                                         \
    }

    // prologue
    ISSUE_A(Aa, apA); ISSUE_B(Ba, bpA);   // phase 0 -> set a
    ISSUE_A(Ab, apB); ISSUE_B(Bb, bpB);   // phase 1 -> set b
    STASH(Aa, c0);                        // waits only set-a A loads (counted)

    for (int t = 0; t < NPH; t += 2) {
        COMPUTE(c0, Ba);                                    // phase t
        if (t + 2 < NPH) { ISSUE_A(Aa, apA); ISSUE_B(Ba, bpA); }   // phase t+2
        STASH(Ab, c1);                                      // A(t+1) -> c1
        COMPUTE(c1, Bb);                                    // phase t+1
        if (t + 3 < NPH) { ISSUE_A(Ab, apB); ISSUE_B(Bb, bpB); }   // phase t+3
        if (t + 2 < NPH) STASH(Aa, c0);                     // A(t+2) -> c0
    }

    // C/D: col(N) = r, row(M) = kg*4 + j  (verified r1-r4)
    const int orow = row0 + kg * 4;
    float* op = out + (size_t)orow * DD + r;
#pragma unroll
    for (int j = 0; j < 4; ++j) {
        op[(size_t)j * DD + 0]  = acc0[j];
        op[(size_t)j * DD + 16] = acc1[j];
        op[(size_t)j * DD + 32] = acc2[j];
        op[(size_t)j * DD + 48] = acc3[j];
    }
}

extern "C" void kernel_launch(void* const* d_in, const int* in_sizes, int n_in,
                              void* d_out, int out_size, void* d_ws, size_t ws_size,
                              hipStream_t stream) {
    const float* x   = (const float*)d_in[0];
    const float* adj = (const float*)d_in[1];
    const float* u   = (const float*)d_in[2];
    float* out = (float*)d_out;
    short* bfrag = (short*)d_ws;   // 16384*64 bf16 = 2 MB

    prep_kernel<<<dim3(512), dim3(256), 0, stream>>>(x, u, bfrag);
    gemm_kernel<<<dim3(NN / MT), dim3(64), 0, stream>>>(adj, bfrag, out);
}